// Round 1
// 400.323 us; speedup vs baseline: 1.4296x; 1.4296x over previous
//
#include <hip/hip_runtime.h>

// LSTMTrafficPredictor: fused 2-layer LSTM + FC head via MFMA.
// B=2048, T=512, IN=4, H1=64, H2=32, FC=16, OUT=1.
//
// R18: PURE-BF16 (drop the hi/lo compensation entirely) + exact-f32 biases
// via MFMA C-init.
// Rationale: R17 counters show an ISSUE-BOUND step (MfmaUtil 35.7 + VALUBusy
// 48.9 ~= 85%; 54 MFMA/SIMD/step x ~19.4cy = ~39% checks out against the
// 16x16x32 ubench ceiling). The compensation scheme is 18 of 27 MFMAs, half
// the z ds_reads, and ~25% of the VALU stream (lo round/sub/round packing,
// a+b merges, acc zero-inits). absmax was 0.0 -> full tolerance budget
// unspent; pure-bf16 per-step err ~2^-9 with forget-gate-contractive
// dynamics should land ~1e-3 at the output.
// Also: all biases moved to f32 MFMA C-init (bb1/bb2 pinned AGPRs) -> no
// bias-column rounding, no acc zero-init / bias-copy movs at all.
// CLOSED AXES (measured in prior session): multi-block/CU overlap (spill),
// MFMA-count cuts on the compensated structure (flat), LDS-read cuts
// (regressed), ACT2 redistribution (regressed - lengthens serial chain).
// Structure: MB=8, BLK=512, grid=256, bounds(512,2), AGPR-pinned frags,
// unroll-2 ping-pong, 1 barrier/step, redistributed ACT1, paired rcp.
// k-map (K=128): [h1(0..63) | x(64..67) | 0(68..95) | h2(96..127)]
//   L1: 2 tiles/wave (unit w*8+nt*4+quad, acc[rg]=gate rg), ks 0..2
//   L2: 1 tile/wave  (unit w*4+quad,      acc[rg]=gate rg), ks {0,1,3}
//   z offset(k,n) = (k>>5)*512 + (((k>>3)&3)*16+n)*8 + (k&7); frag read = lane*8.
// Redistributed ACT1: lane tl -> unit w*8 + (tl>>5)*4 + ((tl>>3)&3), batch tl&7.
// FALLBACK if absmax fails: restore z-lo (state compensation, +9 MFMA) first,
// then W-lo, choosing by the reported absmax magnitude.

#define T_LEN 512
#define IN_F  4
#define H1    64
#define H2    32
#define FCN   16
#define MB    8
#define BLK   512

typedef __attribute__((ext_vector_type(8))) short s8b;  // 8 bf16 = 4 VGPR
typedef __attribute__((ext_vector_type(4))) float f4;   // MFMA acc
typedef __attribute__((ext_vector_type(4))) int   i4;   // 4 dwords (pin unit)

union S8U { s8b v; i4 d; unsigned short u[8]; };
union F4U { f4 v; i4 d; float f[4]; };

// Pin 4 consecutive regs into AGPRs; asm def kills rematerialization.
#define APIN4(x) asm volatile("" : "+a"((x).d))

#define MF(a, b, c) __builtin_amdgcn_mfma_f32_16x16x32_bf16((a), (b), (c), 0, 0, 0)

__device__ __forceinline__ float rcp_(float x) { return __builtin_amdgcn_rcpf(x); }
__device__ __forceinline__ float tanh_(float x) { return 1.0f - 2.0f * rcp_(__expf(2.0f * x) + 1.0f); }

__device__ __forceinline__ unsigned short bf16_rne(float f) {
    unsigned u = __float_as_uint(f);
    u = u + 0x7FFFu + ((u >> 16) & 1u);
    return (unsigned short)(u >> 16);
}

// ---- step-body macros (P = read buffer, NP = write buffer, compile-time) ----
// 9 MFMA/wave/step; bias enters as C-init straight from pinned AGPRs.
#define STEP_MFMA(P)                                                            \
    f4 a1_0, a1_1, ac2;                                                         \
    {                                                                           \
        const s8b z0 = *(const s8b*)(&zz[P][0] + 0 * 512 + offF);               \
        const s8b z1 = *(const s8b*)(&zz[P][0] + 1 * 512 + offF);               \
        const s8b z2 = *(const s8b*)(&zz[P][0] + 2 * 512 + offF);               \
        const s8b z3 = *(const s8b*)(&zz[P][0] + 3 * 512 + offF);               \
        a1_0 = MF(wf1[0][0].v, z0, bb1[0].v);                                   \
        a1_1 = MF(wf1[1][0].v, z0, bb1[1].v);                                   \
        ac2  = MF(wf2[0].v,    z0, bb2.v);                                      \
        a1_0 = MF(wf1[0][1].v, z1, a1_0);                                       \
        a1_1 = MF(wf1[1][1].v, z1, a1_1);                                       \
        ac2  = MF(wf2[1].v,    z1, ac2);                                        \
        a1_0 = MF(wf1[0][2].v, z2, a1_0);                                       \
        a1_1 = MF(wf1[1][2].v, z2, a1_1);                                       \
        ac2  = MF(wf2[2].v,    z3, ac2);                                        \
    }

// L1 activations, redistributed: publish gates to wave scratch, then every
// lane processes ONE (unit,batch) set. Same-wave LDS -> no barrier.
#define STEP_ACT1(NP)                                                           \
    {                                                                           \
        if (col < MB) {                                                         \
            *(f4*)&gsc[w][quad * 8 + col][0]      = a1_0;                       \
            *(f4*)&gsc[w][32 + quad * 8 + col][0] = a1_1;                       \
        }                                                                       \
        const f4 g = *(const f4*)&gsc[w][lane][0];                              \
        const float dI = 1.0f + __expf(-g[0]);                                  \
        const float dF = 1.0f + __expf(-g[1]);                                  \
        const float rIF = rcp_(dI * dF);                                        \
        const float I = dF * rIF, F = dI * rIF;                                 \
        const float dG = __expf(2.0f * g[2]) + 1.0f;                            \
        const float dO = 1.0f + __expf(-g[3]);                                  \
        const float rGO = rcp_(dG * dO);                                        \
        const float G = 1.0f - 2.0f * (dO * rGO), O = dG * rGO;                 \
        c1 = fmaf(F, c1, I * G);                                                \
        zz[NP][offH] = bf16_rne(O * tanh_(c1));                                 \
    }

#define STEP_ACT2(NP)                                                           \
    {                                                                           \
        const float dI = 1.0f + __expf(-ac2[0]);                                \
        const float dF = 1.0f + __expf(-ac2[1]);                                \
        const float rIF = rcp_(dI * dF);                                        \
        const float I = dF * rIF, F = dI * rIF;                                 \
        const float dG = __expf(2.0f * ac2[2]) + 1.0f;                          \
        const float dO = 1.0f + __expf(-ac2[3]);                                \
        const float rGO = rcp_(dG * dO);                                        \
        const float G = 1.0f - 2.0f * (dO * rGO), O = dG * rGO;                 \
        c2 = fmaf(F, c2, I * G);                                                \
        const float h = O * tanh_(c2);                                          \
        if (col < MB) zz[NP][off2] = bf16_rne(h);                               \
    }

__global__ __launch_bounds__(BLK, 2)
void lstm_mfma(const float* __restrict__ x,
               const float* __restrict__ Wih1, const float* __restrict__ Whh1,
               const float* __restrict__ bih1, const float* __restrict__ bhh1,
               const float* __restrict__ Wih2, const float* __restrict__ Whh2,
               const float* __restrict__ bih2, const float* __restrict__ bhh2,
               const float* __restrict__ fc1_w, const float* __restrict__ fc1_b,
               const float* __restrict__ fc2_w, const float* __restrict__ fc2_b,
               float* __restrict__ out)
{
    __shared__ __align__(16) unsigned short zz[2][2048];     // 8 KB
    __shared__ __align__(16) float gsc[8][64][4];            // 8 KB wave scratch
    __shared__ __align__(16) float h2f[MB * H2];
    __shared__ __align__(16) float fcs[MB * FCN];

    const int t    = threadIdx.x;
    const int lane = t & 63;
    const int w    = t >> 6;      // wave 0..7
    const int col  = lane & 15;   // batch col (valid < MB) / A-frag row
    const int quad = lane >> 4;
    const int b0   = blockIdx.x * MB;

    // ---- weight fragments (gate-complete interleaved mapping, bf16) ----
    S8U wf1[2][3];                // layer1: 2 tiles x ks 0..2
    S8U wf2[3];                   // layer2: 1 tile  x ks {0,1,3}
    #pragma unroll
    for (int nt = 0; nt < 2; ++nt) {
        const int r1 = (col & 3) * 64 + w * 8 + nt * 4 + (col >> 2);
        #pragma unroll
        for (int ks = 0; ks < 3; ++ks) {
            #pragma unroll
            for (int j = 0; j < 8; ++j) {
                const int k = ks * 32 + quad * 8 + j;
                float wv = 0.f;
                if      (k < H1)           wv = Whh1[r1 * H1 + k];
                else if (k < H1 + IN_F)    wv = Wih1[r1 * IN_F + (k - H1)];
                wf1[nt][ks].u[j] = bf16_rne(wv);
            }
        }
    }
    {
        const int r2 = (col & 3) * 32 + w * 4 + (col >> 2);
        #pragma unroll
        for (int kf = 0; kf < 3; ++kf) {
            #pragma unroll
            for (int j = 0; j < 8; ++j) {
                const int k = ((kf < 2) ? kf * 32 : 96) + quad * 8 + j;
                const float wv = (k < H1) ? Wih2[r2 * H1 + k]
                                          : Whh2[r2 * H2 + (k - 96)];
                wf2[kf].u[j] = bf16_rne(wv);
            }
        }
    }
    // biases as exact-f32 MFMA C-init (lane's acc rows = 4 gates of its unit)
    const int u2 = w * 4 + quad;              // layer2 unit
    F4U bb1[2], bb2;
    #pragma unroll
    for (int j = 0; j < 4; ++j) {
        const int u1a = w * 8 + quad;         // nt=0 unit
        const int u1b = w * 8 + 4 + quad;     // nt=1 unit
        bb1[0].f[j] = bih1[j * 64 + u1a] + bhh1[j * 64 + u1a];
        bb1[1].f[j] = bih1[j * 64 + u1b] + bhh1[j * 64 + u1b];
        bb2.f[j]    = bih2[j * 32 + u2]  + bhh2[j * 32 + u2];
    }

    // ---- PIN fragments + biases into AGPRs (48 AGPR) ----
    #pragma unroll
    for (int nt = 0; nt < 2; ++nt)
        #pragma unroll
        for (int ks = 0; ks < 3; ++ks) APIN4(wf1[nt][ks]);
    #pragma unroll
    for (int kf = 0; kf < 3; ++kf) APIN4(wf2[kf]);
    APIN4(bb1[0]); APIN4(bb1[1]); APIN4(bb2);

    // ---- init LDS: zero z (both buffers); x(0) ----
    {
        int* pz = (int*)zz;       // 2*2048 shorts = 2048 ints
        #pragma unroll
        for (int i = 0; i < 4; ++i) pz[t + i * BLK] = 0;
    }
    __syncthreads();
    if (t < MB * IN_F) {                    // x(0) at k=64+f: off = 1024 + n*8 + f
        const int n = t >> 2, f = t & 3;
        const float xv = x[(size_t)(b0 + n) * T_LEN * IN_F + f];
        zz[0][1024 + n * 8 + f] = bf16_rne(xv);
    }
    float c1 = 0.f;   // redistributed: unit w*8+(lane>>5)*4+((lane>>3)&3), batch lane&7
    float c2 = 0.f;   // layer2 unit u2, batch col

    // store offsets
    const int uH   = w * 8 + ((lane >> 5) << 2) + ((lane >> 3) & 3);
    const int nH   = lane & 7;
    const int offH = (uH >> 5) * 512 + (((uH >> 3) & 3) * 16 + nH) * 8 + (uH & 7);
    const int off2 = 1536 + (((u2 >> 3) & 3) * 16 + col) * 8 + (u2 & 7);
    const int offF = lane * 8;                     // frag read base
    const int xn_  = (t >> 2) & 7, xf_ = t & 3;    // x-prefetch role (t < 32)
    const float* xp = x + (size_t)(b0 + xn_) * T_LEN * IN_F + IN_F + xf_;  // -> x(1)
    __syncthreads();

    // ================= main recurrence: unrolled x2, 1 barrier/step ==========
    #pragma unroll 1
    for (int s2 = 0; s2 < T_LEN / 2; ++s2) {
        // ---------- body A: s = 2*s2 (read zz[0], write zz[1]) ----------
        {
            float xn = 0.f;
            if (t < MB * IN_F) xn = *xp;           // x(2*s2+1), always valid
            STEP_MFMA(0)
            STEP_ACT1(1)
            if (s2 != 0) STEP_ACT2(1)              // gates2 belong to step s-1
            if (t < MB * IN_F) zz[1][1024 + xn_ * 8 + xf_] = bf16_rne(xn);
            xp += IN_F;
        }
        __syncthreads();
        // ---------- body B: s = 2*s2+1 (read zz[1], write zz[0]) ----------
        {
            float xn = 0.f;
            const bool ld = (t < MB * IN_F) && (s2 != T_LEN / 2 - 1);
            if (ld) xn = *xp;                      // x(2*s2+2)
            STEP_MFMA(1)
            STEP_ACT1(0)
            STEP_ACT2(0)                           // s >= 1 always here
            if (ld) zz[0][1024 + xn_ * 8 + xf_] = bf16_rne(xn);
            xp += IN_F;
        }
        __syncthreads();
    }

    // ================= epilogue: layer2 step T-1 (zz[0]: h1(511), h2(510)) ====
    {
        const s8b z0 = *(const s8b*)(&zz[0][0] + 0 * 512 + offF);
        const s8b z1 = *(const s8b*)(&zz[0][0] + 1 * 512 + offF);
        const s8b z3 = *(const s8b*)(&zz[0][0] + 3 * 512 + offF);
        f4 ac2;
        ac2 = MF(wf2[0].v, z0, bb2.v);
        ac2 = MF(wf2[1].v, z1, ac2);
        ac2 = MF(wf2[2].v, z3, ac2);
        const float dI = 1.0f + __expf(-ac2[0]);
        const float dF = 1.0f + __expf(-ac2[1]);
        const float rIF = rcp_(dI * dF);
        const float I = dF * rIF, F = dI * rIF;
        const float dG = __expf(2.0f * ac2[2]) + 1.0f;
        const float dO = 1.0f + __expf(-ac2[3]);
        const float rGO = rcp_(dG * dO);
        const float G = 1.0f - 2.0f * (dO * rGO), O = dG * rGO;
        c2 = fmaf(F, c2, I * G);
        if (col < MB) h2f[col * H2 + u2] = O * tanh_(c2);
    }
    __syncthreads();

    // ================= FC head =================
    if (t < MB * FCN) {
        const int b = t >> 4, j = t & 15;
        float s1 = fc1_b[j];
        #pragma unroll
        for (int k = 0; k < H2; ++k)
            s1 = fmaf(fc1_w[j * H2 + k], h2f[b * H2 + k], s1);
        fcs[b * FCN + j] = fmaxf(s1, 0.f);
    }
    __syncthreads();
    if (t < MB) {
        float s2v = fc2_b[0];
        #pragma unroll
        for (int j = 0; j < FCN; ++j)
            s2v = fmaf(fc2_w[j], fcs[t * FCN + j], s2v);
        out[b0 + t] = s2v;
    }
}

extern "C" void kernel_launch(void* const* d_in, const int* in_sizes, int n_in,
                              void* d_out, int out_size, void* d_ws, size_t ws_size,
                              hipStream_t stream) {
    const float* x     = (const float*)d_in[0];
    const float* Wih1  = (const float*)d_in[1];
    const float* Whh1  = (const float*)d_in[2];
    const float* bih1  = (const float*)d_in[3];
    const float* bhh1  = (const float*)d_in[4];
    const float* Wih2  = (const float*)d_in[5];
    const float* Whh2  = (const float*)d_in[6];
    const float* bih2  = (const float*)d_in[7];
    const float* bhh2  = (const float*)d_in[8];
    const float* fc1_w = (const float*)d_in[9];
    const float* fc1_b = (const float*)d_in[10];
    const float* fc2_w = (const float*)d_in[11];
    const float* fc2_b = (const float*)d_in[12];
    float* out = (float*)d_out;

    const int n_batch = 2048;
    dim3 grid(n_batch / MB), block(BLK);
    lstm_mfma<<<grid, block, 0, stream>>>(x, Wih1, Whh1, bih1, bhh1,
                                          Wih2, Whh2, bih2, bhh2,
                                          fc1_w, fc1_b, fc2_w, fc2_b, out);
}

// Round 2
// 397.269 us; speedup vs baseline: 1.4406x; 1.0077x over previous
//
#include <hip/hip_runtime.h>

// LSTMTrafficPredictor: fused 2-layer LSTM + FC head via MFMA.
// B=2048, T=512, IN=4, H1=64, H2=32, FC=16, OUT=1.
//
// R19: trans/VALU trim + latency-hiding reorder on the R18 pure-bf16 kernel.
// R18 counter model (357us, 1670cy/step): per SIMD/step = MFMA 350cy
// (18 x 19.4, matches MfmaUtil 18%) + trans 512cy (16 exp/rcp per lane x
// ~16cy/wave64) + regular VALU ~320cy + idle ~490cy. VALUBusy 50% is
// reproduced exactly by the 16cy/trans model -> trans pipe is the largest
// issue consumer.
// R19 changes:
//  (a) exp2-folding: W1/W2 gate rows i,f,o scaled by log2e, gate-g rows by
//      2*log2e (biases identically). Every sigmoid/tanh exp becomes a bare
//      v_exp_f32 with free neg-modifier (no mul). h stays unscaled.
//  (b) v_cvt_pk_bf16_f32 (1 instr) replaces 4-instr bf16_rne at hot stores.
//  (c) body reorder: publish a1 -> issue gsc read -> ACT2 (reg-only trans
//      chain covers the gsc write->read latency) -> ACT1 consume. Previously
//      the round-trip was exposed on the critical path.
// CLOSED AXES (measured): multi-block/CU (reg spill; also MB=4 doubles wasted
// MFMA cols + ACT2 issue), MB=16 (only 128 blocks -> half the CUs idle),
// ACT2 cross-wave redistribution (needs 2nd barrier, R16 regressed),
// non-redistributed ACT1 (2x ACT1 issue > round-trip saved).
// Structure: MB=8, BLK=512, grid=256, bounds(512,2), AGPR-pinned frags,
// unroll-2 ping-pong, 1 barrier/step, redistributed ACT1, paired rcp.
// k-map (K=128): [h1(0..63) | x(64..67) | 0(68..95) | h2(96..127)]
//   L1: 2 tiles/wave (unit w*8+nt*4+quad, acc[rg]=gate rg), ks 0..2
//   L2: 1 tile/wave  (unit w*4+quad,      acc[rg]=gate rg), ks {0,1,3}
//   z offset(k,n) = (k>>5)*512 + (((k>>3)&3)*16+n)*8 + (k&7); frag read = lane*8.
// Redistributed ACT1: lane tl -> unit w*8 + (tl>>5)*4 + ((tl>>3)&3), batch tl&7.

#define T_LEN 512
#define IN_F  4
#define H1    64
#define H2    32
#define FCN   16
#define MB    8
#define BLK   512

typedef __attribute__((ext_vector_type(8))) short s8b;  // 8 bf16 = 4 VGPR
typedef __attribute__((ext_vector_type(4))) float f4;   // MFMA acc
typedef __attribute__((ext_vector_type(4))) int   i4;   // 4 dwords (pin unit)

union S8U { s8b v; i4 d; unsigned short u[8]; };
union F4U { f4 v; i4 d; float f[4]; };

// Pin 4 consecutive regs into AGPRs; asm def kills rematerialization.
#define APIN4(x) asm volatile("" : "+a"((x).d))

#define MF(a, b, c) __builtin_amdgcn_mfma_f32_16x16x32_bf16((a), (b), (c), 0, 0, 0)
#define EX2(x) __builtin_amdgcn_exp2f(x)

#define L2E   1.4426950408889634f
#define L2E2  2.885390081777927f   // 2*log2(e)

__device__ __forceinline__ float rcp_(float x) { return __builtin_amdgcn_rcpf(x); }
// tanh(x) via exp2: 1 - 2/(2^(2x*log2e)+1)
__device__ __forceinline__ float tanh_(float x) {
    return 1.0f - 2.0f * rcp_(EX2(x * L2E2) + 1.0f);
}

__device__ __forceinline__ unsigned short bf16_rne(float f) {   // loader only
    unsigned u = __float_as_uint(f);
    u = u + 0x7FFFu + ((u >> 16) & 1u);
    return (unsigned short)(u >> 16);
}
__device__ __forceinline__ unsigned short bf16_cvt(float f) {   // hot path: 1 instr
    unsigned r;
    asm("v_cvt_pk_bf16_f32 %0, %1, %2" : "=v"(r) : "v"(f), "v"(f));
    return (unsigned short)r;
}

// ---- step-body macros (P = read buffer, NP = write buffer, compile-time) ----
// 9 MFMA/wave/step; bias enters as C-init straight from pinned AGPRs.
#define STEP_MFMA(P)                                                            \
    f4 a1_0, a1_1, ac2;                                                         \
    {                                                                           \
        const s8b z0 = *(const s8b*)(&zz[P][0] + 0 * 512 + offF);               \
        const s8b z1 = *(const s8b*)(&zz[P][0] + 1 * 512 + offF);               \
        const s8b z2 = *(const s8b*)(&zz[P][0] + 2 * 512 + offF);               \
        const s8b z3 = *(const s8b*)(&zz[P][0] + 3 * 512 + offF);               \
        a1_0 = MF(wf1[0][0].v, z0, bb1[0].v);                                   \
        a1_1 = MF(wf1[1][0].v, z0, bb1[1].v);                                   \
        ac2  = MF(wf2[0].v,    z0, bb2.v);                                      \
        a1_0 = MF(wf1[0][1].v, z1, a1_0);                                       \
        a1_1 = MF(wf1[1][1].v, z1, a1_1);                                       \
        ac2  = MF(wf2[1].v,    z1, ac2);                                        \
        a1_0 = MF(wf1[0][2].v, z2, a1_0);                                       \
        a1_1 = MF(wf1[1][2].v, z2, a1_1);                                       \
        ac2  = MF(wf2[2].v,    z3, ac2);                                        \
    }

// Publish summed gates to wave scratch (same-wave LDS -> no barrier).
#define STEP_ACT1_PUB()                                                         \
    if (col < MB) {                                                             \
        *(f4*)&gsc[w][quad * 8 + col][0]      = a1_0;                           \
        *(f4*)&gsc[w][32 + quad * 8 + col][0] = a1_1;                           \
    }

// Gates are pre-scaled: i,f,o rows by log2e; g rows by 2*log2e.
#define STEP_ACT1_FIN(G_, NP)                                                   \
    {                                                                           \
        const float dI = 1.0f + EX2(-(G_)[0]);                                  \
        const float dF = 1.0f + EX2(-(G_)[1]);                                  \
        const float rIF = rcp_(dI * dF);                                        \
        const float I = dF * rIF, F = dI * rIF;                                 \
        const float dG = EX2((G_)[2]) + 1.0f;                                   \
        const float dO = 1.0f + EX2(-(G_)[3]);                                  \
        const float rGO = rcp_(dG * dO);                                        \
        const float Gg = 1.0f - 2.0f * (dO * rGO), O = dG * rGO;                \
        c1 = fmaf(F, c1, I * Gg);                                               \
        zz[NP][offH] = bf16_cvt(O * tanh_(c1));                                 \
    }

#define STEP_ACT2(NP)                                                           \
    {                                                                           \
        const float dI = 1.0f + EX2(-ac2[0]);                                   \
        const float dF = 1.0f + EX2(-ac2[1]);                                   \
        const float rIF = rcp_(dI * dF);                                        \
        const float I = dF * rIF, F = dI * rIF;                                 \
        const float dG = EX2(ac2[2]) + 1.0f;                                    \
        const float dO = 1.0f + EX2(-ac2[3]);                                   \
        const float rGO = rcp_(dG * dO);                                        \
        const float Gg = 1.0f - 2.0f * (dO * rGO), O = dG * rGO;                \
        c2 = fmaf(F, c2, I * Gg);                                               \
        const float h = O * tanh_(c2);                                          \
        if (col < MB) zz[NP][off2] = bf16_cvt(h);                               \
    }

__global__ __launch_bounds__(BLK, 2)
void lstm_mfma(const float* __restrict__ x,
               const float* __restrict__ Wih1, const float* __restrict__ Whh1,
               const float* __restrict__ bih1, const float* __restrict__ bhh1,
               const float* __restrict__ Wih2, const float* __restrict__ Whh2,
               const float* __restrict__ bih2, const float* __restrict__ bhh2,
               const float* __restrict__ fc1_w, const float* __restrict__ fc1_b,
               const float* __restrict__ fc2_w, const float* __restrict__ fc2_b,
               float* __restrict__ out)
{
    __shared__ __align__(16) unsigned short zz[2][2048];     // 8 KB
    __shared__ __align__(16) float gsc[8][64][4];            // 8 KB wave scratch
    __shared__ __align__(16) float h2f[MB * H2];
    __shared__ __align__(16) float fcs[MB * FCN];

    const int t    = threadIdx.x;
    const int lane = t & 63;
    const int w    = t >> 6;      // wave 0..7
    const int col  = lane & 15;   // batch col (valid < MB) / A-frag row
    const int quad = lane >> 4;
    const int b0   = blockIdx.x * MB;

    // ---- weight fragments (gate-complete interleaved mapping, bf16) ----
    // exp2-folding: gate rg = col&3 for both layers; g-gate (rg==2) x 2*log2e.
    const float wsc = ((col & 3) == 2) ? L2E2 : L2E;
    S8U wf1[2][3];                // layer1: 2 tiles x ks 0..2
    S8U wf2[3];                   // layer2: 1 tile  x ks {0,1,3}
    #pragma unroll
    for (int nt = 0; nt < 2; ++nt) {
        const int r1 = (col & 3) * 64 + w * 8 + nt * 4 + (col >> 2);
        #pragma unroll
        for (int ks = 0; ks < 3; ++ks) {
            #pragma unroll
            for (int j = 0; j < 8; ++j) {
                const int k = ks * 32 + quad * 8 + j;
                float wv = 0.f;
                if      (k < H1)           wv = Whh1[r1 * H1 + k];
                else if (k < H1 + IN_F)    wv = Wih1[r1 * IN_F + (k - H1)];
                wf1[nt][ks].u[j] = bf16_rne(wv * wsc);
            }
        }
    }
    {
        const int r2 = (col & 3) * 32 + w * 4 + (col >> 2);
        #pragma unroll
        for (int kf = 0; kf < 3; ++kf) {
            #pragma unroll
            for (int j = 0; j < 8; ++j) {
                const int k = ((kf < 2) ? kf * 32 : 96) + quad * 8 + j;
                const float wv = (k < H1) ? Wih2[r2 * H1 + k]
                                          : Whh2[r2 * H2 + (k - 96)];
                wf2[kf].u[j] = bf16_rne(wv * wsc);
            }
        }
    }
    // biases as exact-f32 MFMA C-init (lane's acc rows = 4 gates of its unit),
    // scaled to match their gate rows.
    const int u2 = w * 4 + quad;              // layer2 unit
    F4U bb1[2], bb2;
    #pragma unroll
    for (int j = 0; j < 4; ++j) {
        const float bsc = (j == 2) ? L2E2 : L2E;
        const int u1a = w * 8 + quad;         // nt=0 unit
        const int u1b = w * 8 + 4 + quad;     // nt=1 unit
        bb1[0].f[j] = (bih1[j * 64 + u1a] + bhh1[j * 64 + u1a]) * bsc;
        bb1[1].f[j] = (bih1[j * 64 + u1b] + bhh1[j * 64 + u1b]) * bsc;
        bb2.f[j]    = (bih2[j * 32 + u2]  + bhh2[j * 32 + u2])  * bsc;
    }

    // ---- PIN fragments + biases into AGPRs (48 AGPR) ----
    #pragma unroll
    for (int nt = 0; nt < 2; ++nt)
        #pragma unroll
        for (int ks = 0; ks < 3; ++ks) APIN4(wf1[nt][ks]);
    #pragma unroll
    for (int kf = 0; kf < 3; ++kf) APIN4(wf2[kf]);
    APIN4(bb1[0]); APIN4(bb1[1]); APIN4(bb2);

    // ---- init LDS: zero z (both buffers); x(0) ----
    {
        int* pz = (int*)zz;       // 2*2048 shorts = 2048 ints
        #pragma unroll
        for (int i = 0; i < 4; ++i) pz[t + i * BLK] = 0;
    }
    __syncthreads();
    if (t < MB * IN_F) {                    // x(0) at k=64+f: off = 1024 + n*8 + f
        const int n = t >> 2, f = t & 3;
        const float xv = x[(size_t)(b0 + n) * T_LEN * IN_F + f];
        zz[0][1024 + n * 8 + f] = bf16_rne(xv);
    }
    float c1 = 0.f;   // redistributed: unit w*8+(lane>>5)*4+((lane>>3)&3), batch lane&7
    float c2 = 0.f;   // layer2 unit u2, batch col

    // store offsets
    const int uH   = w * 8 + ((lane >> 5) << 2) + ((lane >> 3) & 3);
    const int nH   = lane & 7;
    const int offH = (uH >> 5) * 512 + (((uH >> 3) & 3) * 16 + nH) * 8 + (uH & 7);
    const int off2 = 1536 + (((u2 >> 3) & 3) * 16 + col) * 8 + (u2 & 7);
    const int offF = lane * 8;                     // frag read base
    const int xn_  = (t >> 2) & 7, xf_ = t & 3;    // x-prefetch role (t < 32)
    const float* xp = x + (size_t)(b0 + xn_) * T_LEN * IN_F + IN_F + xf_;  // -> x(1)
    __syncthreads();

    // ================= main recurrence: unrolled x2, 1 barrier/step ==========
    #pragma unroll 1
    for (int s2 = 0; s2 < T_LEN / 2; ++s2) {
        // ---------- body A: s = 2*s2 (read zz[0], write zz[1]) ----------
        {
            float xn = 0.f;
            if (t < MB * IN_F) xn = *xp;           // x(2*s2+1), always valid
            STEP_MFMA(0)
            STEP_ACT1_PUB()
            const f4 g_ = *(const f4*)&gsc[w][lane][0];  // read issued early;
            if (s2 != 0) STEP_ACT2(1)              // reg-only chain hides latency
            STEP_ACT1_FIN(g_, 1)
            if (t < MB * IN_F) zz[1][1024 + xn_ * 8 + xf_] = bf16_cvt(xn);
            xp += IN_F;
        }
        __syncthreads();
        // ---------- body B: s = 2*s2+1 (read zz[1], write zz[0]) ----------
        {
            float xn = 0.f;
            const bool ld = (t < MB * IN_F) && (s2 != T_LEN / 2 - 1);
            if (ld) xn = *xp;                      // x(2*s2+2)
            STEP_MFMA(1)
            STEP_ACT1_PUB()
            const f4 g_ = *(const f4*)&gsc[w][lane][0];
            STEP_ACT2(0)                           // s >= 1 always here
            STEP_ACT1_FIN(g_, 0)
            if (ld) zz[0][1024 + xn_ * 8 + xf_] = bf16_cvt(xn);
            xp += IN_F;
        }
        __syncthreads();
    }

    // ================= epilogue: layer2 step T-1 (zz[0]: h1(511), h2(510)) ====
    {
        const s8b z0 = *(const s8b*)(&zz[0][0] + 0 * 512 + offF);
        const s8b z1 = *(const s8b*)(&zz[0][0] + 1 * 512 + offF);
        const s8b z3 = *(const s8b*)(&zz[0][0] + 3 * 512 + offF);
        f4 ac2;
        ac2 = MF(wf2[0].v, z0, bb2.v);
        ac2 = MF(wf2[1].v, z1, ac2);
        ac2 = MF(wf2[2].v, z3, ac2);
        const float dI = 1.0f + EX2(-ac2[0]);
        const float dF = 1.0f + EX2(-ac2[1]);
        const float rIF = rcp_(dI * dF);
        const float I = dF * rIF, F = dI * rIF;
        const float dG = EX2(ac2[2]) + 1.0f;
        const float dO = 1.0f + EX2(-ac2[3]);
        const float rGO = rcp_(dG * dO);
        const float Gg = 1.0f - 2.0f * (dO * rGO), O = dG * rGO;
        c2 = fmaf(F, c2, I * Gg);
        if (col < MB) h2f[col * H2 + u2] = O * tanh_(c2);
    }
    __syncthreads();

    // ================= FC head =================
    if (t < MB * FCN) {
        const int b = t >> 4, j = t & 15;
        float s1 = fc1_b[j];
        #pragma unroll
        for (int k = 0; k < H2; ++k)
            s1 = fmaf(fc1_w[j * H2 + k], h2f[b * H2 + k], s1);
        fcs[b * FCN + j] = fmaxf(s1, 0.f);
    }
    __syncthreads();
    if (t < MB) {
        float s2v = fc2_b[0];
        #pragma unroll
        for (int j = 0; j < FCN; ++j)
            s2v = fmaf(fc2_w[j], fcs[t * FCN + j], s2v);
        out[b0 + t] = s2v;
    }
}

extern "C" void kernel_launch(void* const* d_in, const int* in_sizes, int n_in,
                              void* d_out, int out_size, void* d_ws, size_t ws_size,
                              hipStream_t stream) {
    const float* x     = (const float*)d_in[0];
    const float* Wih1  = (const float*)d_in[1];
    const float* Whh1  = (const float*)d_in[2];
    const float* bih1  = (const float*)d_in[3];
    const float* bhh1  = (const float*)d_in[4];
    const float* Wih2  = (const float*)d_in[5];
    const float* Whh2  = (const float*)d_in[6];
    const float* bih2  = (const float*)d_in[7];
    const float* bhh2  = (const float*)d_in[8];
    const float* fc1_w = (const float*)d_in[9];
    const float* fc1_b = (const float*)d_in[10];
    const float* fc2_w = (const float*)d_in[11];
    const float* fc2_b = (const float*)d_in[12];
    float* out = (float*)d_out;

    const int n_batch = 2048;
    dim3 grid(n_batch / MB), block(BLK);
    lstm_mfma<<<grid, block, 0, stream>>>(x, Wih1, Whh1, bih1, bhh1,
                                          Wih2, Whh2, bih2, bhh2,
                                          fc1_w, fc1_b, fc2_w, fc2_b, out);
}